// Round 9
// baseline (408.298 us; speedup 1.0000x reference)
//
#include <hip/hip_runtime.h>
#include <stdint.h>

#define BB 8
#define SD 512

typedef unsigned short u16;
typedef __attribute__((ext_vector_type(8))) __bf16 bf16x8;
typedef __attribute__((ext_vector_type(16))) float f32x16;

// Static device scratch
__device__ float g_s[BB * 128];
__device__ u16 g_wtb[BB * 9 * 2 * 8192];                  // [b][tap][chunk]: 16KB blocks, [slot][co] 16-B entries
__device__ u16 g_xb[(size_t)BB * 258 * 258 * 128 + 2048]; // [b][gy_p][gx_p][slot] pixel-major, plain slot order

typedef const __attribute__((address_space(1))) uint32_t* gp1;
typedef __attribute__((address_space(3))) uint32_t* lp3;

__device__ __forceinline__ void glds16(const void* g, void* l) {
    __builtin_amdgcn_global_load_lds((gp1)g, (lp3)l, 16, 0, 0);
}
__device__ __forceinline__ void glds4(const void* g, void* l) {
    __builtin_amdgcn_global_load_lds((gp1)g, (lp3)l, 4, 0, 0);
}

__device__ __forceinline__ u16 f2bf(float f) {
    uint32_t u = __float_as_uint(f);
    u += 0x7FFFu + ((u >> 16) & 1u);   // RNE
    return (u16)(u >> 16);
}

__global__ void affine_kernel(const float* __restrict__ style,
                              const float* __restrict__ aff_w,
                              const float* __restrict__ aff_b) {
    int b = blockIdx.x;
    int ci = threadIdx.x;
    const float gain = 0.044194173824159216f;  // 1/sqrt(512)
    const float* st = style + b * SD;
    const float* aw = aff_w + ci * SD;
    float acc = 0.f;
    #pragma unroll 8
    for (int j = 0; j < SD; ++j) acc += st[j] * aw[j];
    g_s[b * 128 + ci] = acc * gain + aff_b[ci];
}

__global__ __launch_bounds__(256) void modulate_kernel(const float* __restrict__ w_base) {
    int blk = blockIdx.x;           // 0..B*CO-1
    int b = blk >> 7, co = blk & 127;
    int tid = threadIdx.x;
    const float wgain = 0.029462782549439483f;  // 1/sqrt(128*9)
    const int n = 1152;
    const float* wb = w_base + co * n;
    const float* sp = g_s + b * 128;

    float v[5];
    float sq = 0.f;
    #pragma unroll
    for (int i = 0; i < 5; ++i) {
        int idx = tid + i * 256;
        float w = 0.f;
        if (idx < n) {
            int ci = idx / 9;
            w = wb[idx] * wgain * sp[ci];
        }
        v[i] = w;
        sq += w * w;
    }
    #pragma unroll
    for (int off = 32; off > 0; off >>= 1) sq += __shfl_down(sq, off, 64);
    __shared__ float red[4];
    int lane = tid & 63, wvi = tid >> 6;
    if (lane == 0) red[wvi] = sq;
    __syncthreads();
    float tot = red[0] + red[1] + red[2] + red[3];
    float d = rsqrtf(tot + 1e-8f);
    #pragma unroll
    for (int i = 0; i < 5; ++i) {
        int idx = tid + i * 256;
        if (idx < n) {
            int ci = idx / 9;
            int k9 = idx - ci * 9;              // tap
            u16 hv = f2bf(v[i] * d);
            // block [b][tap][chunk]; within: entry (slot, co), u16 pos e
            int slot = (ci & 63) >> 3, e = ci & 7;
            size_t base = ((size_t)(b * 9 + k9) * 2 + (ci >> 6)) * 8192;
            g_wtb[base + slot * 1024 + co * 8 + e] = hv;
        }
    }
}

// zero halo borders of g_xb (pixel-major)
__global__ __launch_bounds__(256) void zero_border_kernel() {
    int b = blockIdx.x;
    uint4 z = make_uint4(0, 0, 0, 0);
    char* xbB = (char*)g_xb;
    for (int i = threadIdx.x; i < 16448; i += 256) {
        size_t pix; int k;
        if (i < 4128)       { pix = (size_t)(b * 258 + 0)   * 258 + (i >> 4);            k = i & 15; }
        else if (i < 8256)  { int j = i - 4128;  pix = (size_t)(b * 258 + 257) * 258 + (j >> 4);       k = j & 15; }
        else if (i < 12352) { int j = i - 8256;  pix = (size_t)(b * 258 + 1 + (j >> 4)) * 258 + 0;     k = j & 15; }
        else                { int j = i - 12352; pix = (size_t)(b * 258 + 1 + (j >> 4)) * 258 + 257;   k = j & 15; }
        *(uint4*)(xbB + pix * 256 + (size_t)k * 16) = z;
    }
}

// transpose+convert: x [b][ci][h][w] fp32 -> g_xb [b][gy_p][gx_p][slot] bf16 (plain slot order)
__global__ __launch_bounds__(256) void transpose_kernel(const float* __restrict__ x) {
    __shared__ __align__(16) u16 t_lds[64 * 128];   // 16 KB
    const int chunk = blockIdx.x;        // 0..3 (64-px chunk)
    const int gy = blockIdx.y;           // 0..255
    const int b = blockIdx.z;
    const int px0 = chunk * 64;
    const int tid = threadIdx.x;
    const int pq = tid & 15;             // pixel quad: px = pq*4 + j
    const int cig = tid >> 4;            // 16-B ci group (8 ci), 0..15

    const float* base = x + (size_t)b * 128 * 65536 + (size_t)gy * 256 + px0 + pq * 4;
    char* ldsB = (char*)t_lds;

    float4 v[8];
    #pragma unroll
    for (int c = 0; c < 8; ++c)
        v[c] = *(const float4*)(base + (size_t)(cig * 8 + c) * 65536);

    #pragma unroll
    for (int j = 0; j < 4; ++j) {
        uint32_t dw[4];
        #pragma unroll
        for (int d = 0; d < 4; ++d) {
            const float* lo4 = (const float*)&v[2 * d];
            const float* hi4 = (const float*)&v[2 * d + 1];
            dw[d] = (uint32_t)f2bf(lo4[j]) | ((uint32_t)f2bf(hi4[j]) << 16);
        }
        int px = pq * 4 + j;                 // within chunk
        int key = (px0 + px + 1) & 7;        // LDS bank-spread only
        int slot = cig ^ key;
        *(uint4*)(ldsB + px * 256 + slot * 16) = *(uint4*)dw;
    }
    __syncthreads();

    // write out: 256 B contiguous per pixel, plain slot order
    char* outB = (char*)g_xb;
    #pragma unroll
    for (int it = 0; it < 4; ++it) {
        int flat = it * 256 + tid;
        int r = flat >> 4, k = flat & 15;    // pixel r, true ci-group k
        int key = (px0 + r + 1) & 7;
        uint4 val = *(const uint4*)(ldsB + r * 256 + ((k ^ key) << 4));
        size_t pix = ((size_t)(b * 258 + gy + 1)) * 258 + (px0 + r + 1);
        *(uint4*)(outB + pix * 256 + k * 16) = val;
    }
}

// Implicit-GEMM conv: per block: batch b, 32x8 px tile, all 128 co. 512 threads.
// 32x32x16 MFMA; LDS plane-major (conflict-free) filled from pixel-major g_xb
// via per-lane source addressing (linear LDS dest). 76288 B LDS -> 2 blocks/CU.
__global__ __launch_bounds__(512, 4) void conv_kernel(float* __restrict__ y) {
    __shared__ __align__(16) u16 xs[2720 * 8];        // [slot][row][col] 16-B entries, 43520 B
    __shared__ __align__(16) u16 ab[2][8192];         // A double buffer, 2x16 KB

    const int b = blockIdx.y;
    const int t = blockIdx.x;                 // 0..255
    const int swzt = (t & 7) * 32 + (t >> 3); // XCD-aware swizzle (256 % 8 == 0)
    const int tx = swzt & 7, ty = swzt >> 3;
    const int y0 = ty * 8, x0 = tx * 32;
    const int tid = threadIdx.x;
    const int lane = tid & 63, wv = tid >> 6;
    const int l31 = lane & 31;                // px-col / co-row within MFMA tile
    const int l5 = lane >> 5;                 // k-group select
    const int coHalf = (wv & 1) * 64;         // wave co origin
    const int py0w = (wv >> 1) * 2;           // wave row origin (2 rows/wave)

    const char* xbB = (const char*)g_xb;
    const char* wtbB = (const char*)(g_wtb) + (size_t)b * 294912;
    char* xsB = (char*)xs;

    f32x16 acc[2][2];
    #pragma unroll
    for (int mf = 0; mf < 2; ++mf)
        #pragma unroll
        for (int rf = 0; rf < 2; ++rf)
            acc[mf][rf] = (f32x16){0.f};

    for (int h = 0; h < 2; ++h) {
        // ---- stage X ci-half h: 2720 LDS entries; linear LDS dest, per-lane px-major src ----
        for (int i = wv; i < 44; i += 8) {
            if (i < 42) {
                int entry = i * 64 + lane;
                int slot = entry / 340;
                int rem = entry - slot * 340;
                int row = rem / 34;
                int col = rem - row * 34;
                size_t pix = (size_t)(b * 258 + y0 + row) * 258 + (x0 + col);
                glds16(xbB + pix * 256 + h * 128 + slot * 16, xsB + i * 1024);
            } else {
                int j = i - 42;
                int entry = 2688 + j * 16 + (lane >> 2);   // all slot 7
                int rem = entry - 2380;
                int row = rem / 34;
                int col = rem - row * 34;
                size_t pix = (size_t)(b * 258 + y0 + row) * 258 + (x0 + col);
                glds4(xbB + pix * 256 + h * 128 + 112 + (lane & 3) * 4,
                      xsB + 43008 + j * 256);
            }
        }
        if (h == 0) {
            // stage A step 0 (tap 0, chunk 0)
            #pragma unroll
            for (int q = 0; q < 2; ++q) {
                int j = wv * 2 + q;
                glds16(wtbB + j * 1024 + lane * 16, (char*)ab[0] + j * 1024);
            }
        }
        __syncthreads();

        for (int tap = 0; tap < 9; ++tap) {
            int s = h * 9 + tap;
            if (s < 17) {
                int ns = s + 1;
                int ntap = (ns >= 9) ? (ns - 9) : ns;
                int nh = (ns >= 9) ? 1 : h;
                const char* src = wtbB + (ntap * 2 + nh) * 16384;
                char* dst = (char*)ab[ns & 1];
                #pragma unroll
                for (int q = 0; q < 2; ++q) {
                    int j = wv * 2 + q;
                    glds16(src + j * 1024 + lane * 16, dst + j * 1024);
                }
            }

            const int ky = tap / 3, kx = tap - ky * 3;
            const char* abuf = (const char*)ab[s & 1];
            const int brow = (py0w + ky) * 34 + l31 + kx;   // entry base (row,col)

            #pragma unroll
            for (int ks = 0; ks < 4; ++ks) {           // K = 64 per half, steps of 16
                const int cig = ks * 2 + l5;           // slot 0..7
                bf16x8 af[2];
                #pragma unroll
                for (int mf = 0; mf < 2; ++mf) {
                    int co = coHalf + mf * 32 + l31;
                    af[mf] = *(const bf16x8*)(abuf + cig * 2048 + co * 16);
                }
                bf16x8 bf[2];
                #pragma unroll
                for (int rf = 0; rf < 2; ++rf)
                    bf[rf] = *(const bf16x8*)(xsB + (cig * 340 + brow + rf * 34) * 16);
                __builtin_amdgcn_s_setprio(1);
                #pragma unroll
                for (int mf = 0; mf < 2; ++mf)
                    #pragma unroll
                    for (int rf = 0; rf < 2; ++rf)
                        acc[mf][rf] = __builtin_amdgcn_mfma_f32_32x32x16_bf16(
                            af[mf], bf[rf], acc[mf][rf], 0, 0, 0);
                __builtin_amdgcn_s_setprio(0);
            }
            __syncthreads();
        }
    }

    // ---- epilogue: C layout (32x32): col = lane&31, row = (j&3)+8*(j>>2)+4*(lane>>5) ----
    float* yb = y + (size_t)b * 128 * 65536;
    #pragma unroll
    for (int mf = 0; mf < 2; ++mf) {
        #pragma unroll
        for (int rf = 0; rf < 2; ++rf) {
            int gy = y0 + py0w + rf;
            int gx = x0 + l31;
            #pragma unroll
            for (int j = 0; j < 16; ++j) {
                int co = coHalf + mf * 32 + (j & 3) + 8 * (j >> 2) + 4 * l5;
                yb[(size_t)co * 65536 + gy * 256 + gx] = acc[mf][rf][j];
            }
        }
    }
}

extern "C" void kernel_launch(void* const* d_in, const int* in_sizes, int n_in,
                              void* d_out, int out_size, void* d_ws, size_t ws_size,
                              hipStream_t stream) {
    const float* x = (const float*)d_in[0];
    const float* style = (const float*)d_in[1];
    const float* w_base = (const float*)d_in[2];
    const float* aff_w = (const float*)d_in[3];
    const float* aff_b = (const float*)d_in[4];
    float* y = (float*)d_out;

    affine_kernel<<<BB, 128, 0, stream>>>(style, aff_w, aff_b);
    modulate_kernel<<<BB * 128, 256, 0, stream>>>(w_base);
    zero_border_kernel<<<BB, 256, 0, stream>>>();
    transpose_kernel<<<dim3(4, 256, BB), 256, 0, stream>>>(x);
    conv_kernel<<<dim3(256, BB), 512, 0, stream>>>(y);
}

// Round 10
// 338.229 us; speedup vs baseline: 1.2072x; 1.2072x over previous
//
#include <hip/hip_runtime.h>
#include <stdint.h>

#define BB 8
#define SD 512

typedef unsigned short u16;
typedef __attribute__((ext_vector_type(8))) __bf16 bf16x8;
typedef __attribute__((ext_vector_type(16))) float f32x16;

// Static device scratch
__device__ float g_s[BB * 128];
__device__ u16 g_wtb[BB * 9 * 2 * 8192];                  // [b][tap][chunk]: 16KB blocks, [slot][co] 16-B entries
__device__ u16 g_xb[(size_t)BB * 258 * 258 * 128 + 2048]; // [b][gy_p][gx_p][slot] pixel-major, plain slot order

typedef const __attribute__((address_space(1))) uint32_t* gp1;
typedef __attribute__((address_space(3))) uint32_t* lp3;

__device__ __forceinline__ void glds16(const void* g, void* l) {
    __builtin_amdgcn_global_load_lds((gp1)g, (lp3)l, 16, 0, 0);
}

__device__ __forceinline__ u16 f2bf(float f) {
    uint32_t u = __float_as_uint(f);
    u += 0x7FFFu + ((u >> 16) & 1u);   // RNE
    return (u16)(u >> 16);
}

__global__ void affine_kernel(const float* __restrict__ style,
                              const float* __restrict__ aff_w,
                              const float* __restrict__ aff_b) {
    int b = blockIdx.x;
    int ci = threadIdx.x;
    const float gain = 0.044194173824159216f;  // 1/sqrt(512)
    const float* st = style + b * SD;
    const float* aw = aff_w + ci * SD;
    float acc = 0.f;
    #pragma unroll 8
    for (int j = 0; j < SD; ++j) acc += st[j] * aw[j];
    g_s[b * 128 + ci] = acc * gain + aff_b[ci];
}

__global__ __launch_bounds__(256) void modulate_kernel(const float* __restrict__ w_base) {
    int blk = blockIdx.x;           // 0..B*CO-1
    int b = blk >> 7, co = blk & 127;
    int tid = threadIdx.x;
    const float wgain = 0.029462782549439483f;  // 1/sqrt(128*9)
    const int n = 1152;
    const float* wb = w_base + co * n;
    const float* sp = g_s + b * 128;

    float v[5];
    float sq = 0.f;
    #pragma unroll
    for (int i = 0; i < 5; ++i) {
        int idx = tid + i * 256;
        float w = 0.f;
        if (idx < n) {
            int ci = idx / 9;
            w = wb[idx] * wgain * sp[ci];
        }
        v[i] = w;
        sq += w * w;
    }
    #pragma unroll
    for (int off = 32; off > 0; off >>= 1) sq += __shfl_down(sq, off, 64);
    __shared__ float red[4];
    int lane = tid & 63, wvi = tid >> 6;
    if (lane == 0) red[wvi] = sq;
    __syncthreads();
    float tot = red[0] + red[1] + red[2] + red[3];
    float d = rsqrtf(tot + 1e-8f);
    #pragma unroll
    for (int i = 0; i < 5; ++i) {
        int idx = tid + i * 256;
        if (idx < n) {
            int ci = idx / 9;
            int k9 = idx - ci * 9;              // tap
            u16 hv = f2bf(v[i] * d);
            // block [b][tap][chunk(h)]; within: entry (slot, co)
            int slot = (ci & 63) >> 3, e = ci & 7;
            size_t base = ((size_t)(b * 9 + k9) * 2 + (ci >> 6)) * 8192;
            g_wtb[base + slot * 1024 + co * 8 + e] = hv;
        }
    }
}

// zero halo borders of g_xb (pixel-major)
__global__ __launch_bounds__(256) void zero_border_kernel() {
    int b = blockIdx.x;
    uint4 z = make_uint4(0, 0, 0, 0);
    char* xbB = (char*)g_xb;
    for (int i = threadIdx.x; i < 16448; i += 256) {
        size_t pix; int k;
        if (i < 4128)       { pix = (size_t)(b * 258 + 0)   * 258 + (i >> 4);            k = i & 15; }
        else if (i < 8256)  { int j = i - 4128;  pix = (size_t)(b * 258 + 257) * 258 + (j >> 4);       k = j & 15; }
        else if (i < 12352) { int j = i - 8256;  pix = (size_t)(b * 258 + 1 + (j >> 4)) * 258 + 0;     k = j & 15; }
        else                { int j = i - 12352; pix = (size_t)(b * 258 + 1 + (j >> 4)) * 258 + 257;   k = j & 15; }
        *(uint4*)(xbB + pix * 256 + (size_t)k * 16) = z;
    }
}

// transpose+convert: x [b][ci][h][w] fp32 -> g_xb [b][gy_p][gx_p][slot] bf16 (plain slot order)
__global__ __launch_bounds__(256) void transpose_kernel(const float* __restrict__ x) {
    __shared__ __align__(16) u16 t_lds[64 * 128];   // 16 KB
    const int chunk = blockIdx.x;        // 0..3 (64-px chunk)
    const int gy = blockIdx.y;           // 0..255
    const int b = blockIdx.z;
    const int px0 = chunk * 64;
    const int tid = threadIdx.x;
    const int pq = tid & 15;             // pixel quad: px = pq*4 + j
    const int cig = tid >> 4;            // 16-B ci group (8 ci), 0..15

    const float* base = x + (size_t)b * 128 * 65536 + (size_t)gy * 256 + px0 + pq * 4;
    char* ldsB = (char*)t_lds;

    float4 v[8];
    #pragma unroll
    for (int c = 0; c < 8; ++c)
        v[c] = *(const float4*)(base + (size_t)(cig * 8 + c) * 65536);

    #pragma unroll
    for (int j = 0; j < 4; ++j) {
        uint32_t dw[4];
        #pragma unroll
        for (int d = 0; d < 4; ++d) {
            const float* lo4 = (const float*)&v[2 * d];
            const float* hi4 = (const float*)&v[2 * d + 1];
            dw[d] = (uint32_t)f2bf(lo4[j]) | ((uint32_t)f2bf(hi4[j]) << 16);
        }
        int px = pq * 4 + j;                 // within chunk
        int key = (px0 + px + 1) & 7;        // LDS bank-spread only
        int slot = cig ^ key;
        *(uint4*)(ldsB + px * 256 + slot * 16) = *(uint4*)dw;
    }
    __syncthreads();

    // write out: 256 B contiguous per pixel, plain slot order
    char* outB = (char*)g_xb;
    #pragma unroll
    for (int it = 0; it < 4; ++it) {
        int flat = it * 256 + tid;
        int r = flat >> 4, k = flat & 15;    // pixel r, true ci-group k
        int key = (px0 + r + 1) & 7;
        uint4 val = *(const uint4*)(ldsB + r * 256 + ((k ^ key) << 4));
        size_t pix = ((size_t)(b * 258 + gy + 1)) * 258 + (px0 + r + 1);
        *(uint4*)(outB + pix * 256 + k * 16) = val;
    }
}

// Implicit-GEMM conv: per block: batch b, 32x8 px tile, all 128 co. 512 threads.
// 32x32x16 MFMA; reg-staged X (coalesced pixel-major global loads -> plane-major LDS
// ds_write_b128), slot-major A via linear glds16. Conflict-free fragment reads.
__global__ __launch_bounds__(512, 4) void conv_kernel(float* __restrict__ y) {
    __shared__ __align__(16) u16 xs[2720 * 8];        // plane-major: entry(s,p)=s*340+p, 43520 B
    __shared__ __align__(16) u16 ab[2][8192];         // A double buffer, 2x16 KB

    const int b = blockIdx.y;
    const int t = blockIdx.x;                 // 0..255
    const int swzt = (t & 7) * 32 + (t >> 3); // XCD-aware swizzle (256 % 8 == 0)
    const int tx = swzt & 7, ty = swzt >> 3;
    const int y0 = ty * 8, x0 = tx * 32;
    const int tid = threadIdx.x;
    const int lane = tid & 63, wv = tid >> 6;
    const int l31 = lane & 31;                // px-col / co-row within MFMA tile
    const int l5 = lane >> 5;                 // k-group select
    const int coHalf = (wv & 1) * 64;         // wave co origin
    const int py0w = (wv >> 1) * 2;           // wave row origin (2 rows/wave)

    const char* xbB = (const char*)g_xb;
    const char* wtbB = (const char*)(g_wtb) + (size_t)b * 294912;
    char* xsB = (char*)xs;

    f32x16 acc[2][2];
    #pragma unroll
    for (int mf = 0; mf < 2; ++mf)
        #pragma unroll
        for (int rf = 0; rf < 2; ++rf)
            acc[mf][rf] = (f32x16){0.f};

    // ---- issue h0 loads (coalesced: 8 slots x consecutive pixels) ----
    uint4 va[6], vb[6];
    #pragma unroll
    for (int it = 0; it < 6; ++it) {
        int f = it * 512 + tid;
        if (f < 2720) {
            int p = f >> 3, s2 = f & 7;
            int row = p / 34, col = p - row * 34;
            size_t pix = (size_t)(b * 258 + y0 + row) * 258 + (x0 + col);
            va[it] = *(const uint4*)(xbB + pix * 256 + s2 * 16);
        }
    }
    // ---- write h0 to plane-major LDS ----
    #pragma unroll
    for (int it = 0; it < 6; ++it) {
        int f = it * 512 + tid;
        if (f < 2720) {
            int p = f >> 3, s2 = f & 7;
            *(uint4*)(xsB + (size_t)(s2 * 340 + p) * 16) = va[it];
        }
    }
    // ---- issue h1 loads (in flight across all h0 taps) ----
    #pragma unroll
    for (int it = 0; it < 6; ++it) {
        int f = it * 512 + tid;
        if (f < 2720) {
            int p = f >> 3, s2 = f & 7;
            int row = p / 34, col = p - row * 34;
            size_t pix = (size_t)(b * 258 + y0 + row) * 258 + (x0 + col);
            vb[it] = *(const uint4*)(xbB + pix * 256 + 128 + s2 * 16);
        }
    }
    // ---- stage A step 0 (tap 0, h 0) ----
    #pragma unroll
    for (int q = 0; q < 2; ++q) {
        int j = wv * 2 + q;
        glds16(wtbB + j * 1024 + lane * 16, (char*)ab[0] + j * 1024);
    }
    __syncthreads();

    #pragma unroll 1
    for (int s = 0; s < 18; ++s) {
        if (s < 17) {
            int ns = s + 1;
            int ntap = (ns >= 9) ? (ns - 9) : ns;
            int nh = (ns >= 9) ? 1 : 0;
            const char* src = wtbB + (ntap * 2 + nh) * 16384;
            char* dst = (char*)ab[ns & 1];
            #pragma unroll
            for (int q = 0; q < 2; ++q) {
                int j = wv * 2 + q;
                glds16(src + j * 1024 + lane * 16, dst + j * 1024);
            }
        }

        const int tap = (s >= 9) ? (s - 9) : s;
        const int ky = tap / 3, kx = tap - ky * 3;
        const char* abuf = (const char*)ab[s & 1];
        const int prow = (py0w + ky) * 34 + l31 + kx;   // pixel index for rf=0

        #pragma unroll
        for (int ks = 0; ks < 4; ++ks) {           // K = 64 per half, steps of 16
            const int cig = ks * 2 + l5;           // plane 0..7
            bf16x8 af[2];
            #pragma unroll
            for (int mf = 0; mf < 2; ++mf) {
                int co = coHalf + mf * 32 + l31;
                af[mf] = *(const bf16x8*)(abuf + cig * 2048 + co * 16);
            }
            bf16x8 bf[2];
            #pragma unroll
            for (int rf = 0; rf < 2; ++rf)
                bf[rf] = *(const bf16x8*)(xsB + (size_t)(cig * 340 + prow + rf * 34) * 16);
            __builtin_amdgcn_s_setprio(1);
            #pragma unroll
            for (int mf = 0; mf < 2; ++mf)
                #pragma unroll
                for (int rf = 0; rf < 2; ++rf)
                    acc[mf][rf] = __builtin_amdgcn_mfma_f32_32x32x16_bf16(
                        af[mf], bf[rf], acc[mf][rf], 0, 0, 0);
            __builtin_amdgcn_s_setprio(0);
        }
        __syncthreads();

        if (s == 8) {
            // swap X tile to ci-half 1 (loads long since landed)
            #pragma unroll
            for (int it = 0; it < 6; ++it) {
                int f = it * 512 + tid;
                if (f < 2720) {
                    int p = f >> 3, s2 = f & 7;
                    *(uint4*)(xsB + (size_t)(s2 * 340 + p) * 16) = vb[it];
                }
            }
            __syncthreads();
        }
    }

    // ---- epilogue: C layout (32x32): col = lane&31, row = (j&3)+8*(j>>2)+4*(lane>>5) ----
    float* yb = y + (size_t)b * 128 * 65536;
    #pragma unroll
    for (int mf = 0; mf < 2; ++mf) {
        #pragma unroll
        for (int rf = 0; rf < 2; ++rf) {
            int gy = y0 + py0w + rf;
            int gx = x0 + l31;
            #pragma unroll
            for (int j = 0; j < 16; ++j) {
                int co = coHalf + mf * 32 + (j & 3) + 8 * (j >> 2) + 4 * l5;
                yb[(size_t)co * 65536 + gy * 256 + gx] = acc[mf][rf][j];
            }
        }
    }
}

extern "C" void kernel_launch(void* const* d_in, const int* in_sizes, int n_in,
                              void* d_out, int out_size, void* d_ws, size_t ws_size,
                              hipStream_t stream) {
    const float* x = (const float*)d_in[0];
    const float* style = (const float*)d_in[1];
    const float* w_base = (const float*)d_in[2];
    const float* aff_w = (const float*)d_in[3];
    const float* aff_b = (const float*)d_in[4];
    float* y = (float*)d_out;

    affine_kernel<<<BB, 128, 0, stream>>>(style, aff_w, aff_b);
    modulate_kernel<<<BB * 128, 256, 0, stream>>>(w_base);
    zero_border_kernel<<<BB, 256, 0, stream>>>();
    transpose_kernel<<<dim3(4, 256, BB), 256, 0, stream>>>(x);
    conv_kernel<<<dim3(256, BB), 512, 0, stream>>>(y);
}